// Round 12
// baseline (339.259 us; speedup 1.0000x reference)
//
#include <hip/hip_runtime.h>
#include <stdint.h>

#define FEAT_STRIDE_I 16
#define A_NUM 9
#define HH 128
#define WW 128
#define NPIX (HH * WW)            // 16384
#define N_ANCH (NPIX * A_NUM)     // 147456
#define B_NUM 8
#define PRE_NMS 6000
#define POST_NMS 300
#define NMS_THRESH_F 0.7f
#define MIN_SIZE_F 16.0f
#define NEG_INF_F -1e30f

#define NB3 16384                  // 14-bit bins (key>>18)
#define SW3(i) ((i) + ((i) >> 5))  // LDS swizzle
#define SEGL 8192                  // in-LDS candidate segment cap

#define RT_TILES 94                // ceil(6000/64)
#define GT_TILES 600               // sum_R ceil((94-R)/8): 8-column groups
#define BQWORDS (RT_TILES * RT_TILES * 64)   // 565,504 qwords per batch

// ---- workspace layout (bytes) ----
#define OFF_KEYS  0u               // 8*147456*4 = 4,718,592
#define OFF_BOXES 4718592u         // 8*6000*4*4 = 768,000
#define OFF_MASK  5486592u         // 8*565504*8 = 36,192,256 -> end 41.7 MB
#define MASK_BYTES ((size_t)B_NUM * BQWORDS * 8)

__device__ __forceinline__ unsigned sortable_f32(float f) {
    unsigned u = __float_as_uint(f);
    return (u & 0x80000000u) ? ~u : (u | 0x80000000u);
}

// Decode one anchor's box exactly in the reference's op order.
__device__ __forceinline__ void decode_box(
    int b, int idx,
    const float* __restrict__ deltas, const float* __restrict__ im_info,
    const float* __restrict__ anchors,
    float& x1, float& y1, float& x2, float& y2, bool& valid)
{
    int a   = idx % A_NUM;
    int pix = idx / A_NUM;
    int w   = pix & (WW - 1);
    int h   = pix >> 7;

    float a0 = anchors[a * 4 + 0];
    float a1 = anchors[a * 4 + 1];
    float a2 = anchors[a * 4 + 2];
    float a3 = anchors[a * 4 + 3];

    float aw = __fadd_rn(__fsub_rn(a2, a0), 1.0f);
    float ah = __fadd_rn(__fsub_rn(a3, a1), 1.0f);
    float sx = (float)(w * FEAT_STRIDE_I);
    float sy = (float)(h * FEAT_STRIDE_I);
    float acx = __fadd_rn(__fadd_rn(sx, a0), __fmul_rn(0.5f, aw));
    float acy = __fadd_rn(__fadd_rn(sy, a1), __fmul_rn(0.5f, ah));

    size_t base = ((size_t)b * 36 + 4 * a) * NPIX + pix;
    float dx = deltas[base];
    float dy = deltas[base + NPIX];
    float dw = deltas[base + 2 * (size_t)NPIX];
    float dh = deltas[base + 3 * (size_t)NPIX];

    float pcx = __fadd_rn(__fmul_rn(dx, aw), acx);
    float pcy = __fadd_rn(__fmul_rn(dy, ah), acy);
    float pw  = __fmul_rn(expf(dw), aw);
    float ph  = __fmul_rn(expf(dh), ah);

    float hx = __fmul_rn(0.5f, pw);
    float hy = __fmul_rn(0.5f, ph);
    x1 = __fsub_rn(pcx, hx);
    y1 = __fsub_rn(pcy, hy);
    x2 = __fadd_rn(pcx, hx);
    y2 = __fadd_rn(pcy, hy);

    float im_h = im_info[b * 3 + 0];
    float im_w = im_info[b * 3 + 1];
    float sc   = im_info[b * 3 + 2];
    float wmax = __fsub_rn(im_w, 1.0f);
    float hmax = __fsub_rn(im_h, 1.0f);

    x1 = fminf(fmaxf(x1, 0.0f), wmax);
    y1 = fminf(fmaxf(y1, 0.0f), hmax);
    x2 = fminf(fmaxf(x2, 0.0f), wmax);
    y2 = fminf(fmaxf(y2, 0.0f), hmax);

    float min_sz = __fmul_rn(MIN_SIZE_F, sc);
    valid = (__fadd_rn(__fsub_rn(x2, x1), 1.0f) >= min_sz) &&
            (__fadd_rn(__fsub_rn(y2, y1), 1.0f) >= min_sz);
}

// K1: decode + masked score -> sortable key. Pure streaming, no atomics.
__global__ void k_decode(
    const float* __restrict__ scores, const float* __restrict__ deltas,
    const float* __restrict__ im_info, const float* __restrict__ anchors,
    unsigned* __restrict__ keys)
{
    int gt = blockIdx.x * blockDim.x + threadIdx.x;
    if (gt >= B_NUM * N_ANCH) return;
    int pix  = gt & (NPIX - 1);
    int rest = gt >> 14;
    int a = rest % A_NUM;
    int b = rest / A_NUM;
    int idx = pix * A_NUM + a;

    float x1, y1, x2, y2; bool valid;
    decode_box(b, idx, deltas, im_info, anchors, x1, y1, x2, y2, valid);

    float s = scores[((size_t)b * 18 + 9 + a) * NPIX + pix];
    if (!valid) s = NEG_INF_F;
    keys[gt] = sortable_f32(s);
}

// K2 (fused): per-batch top-6000 selection entirely in LDS.
// hist(14-bit bins) -> suffix scan -> threshold T -> scatter into in-LDS
// bin-segmented array (slot alloc = atomicAdd on the binbase array itself;
// post-alloc hb[bin] = segment END, and segment BASE = post-alloc hb[bin+1]
// via the descending-bin identity binbase[b-1] = binbase[b] + hist[b]) ->
// exact in-bin rank -> decode box straight into its sorted slot.
// Replaces 3 kernels + memset; no global hist/seg round-trips.
__global__ __launch_bounds__(1024) void k_select(
    const unsigned* __restrict__ keys,
    const float* __restrict__ deltas, const float* __restrict__ im_info,
    const float* __restrict__ anchors, float* __restrict__ boxes)
{
    __shared__ unsigned hb[SW3(NB3 - 1) + 2];      // 67.6 KB
    __shared__ unsigned long long segl[SEGL];      // 64 KB
    __shared__ unsigned csum[1024];
    __shared__ unsigned sT, sCnt;

    int b = blockIdx.x;
    int t = threadIdx.x;
    if (t == 0) { sT = 0; sCnt = 0; }
    for (int i = t; i < SW3(NB3 - 1) + 2; i += 1024) hb[i] = 0u;
    __syncthreads();

    // 1) histogram
    const unsigned* kb = keys + (size_t)b * N_ANCH;
    for (int i = t; i < N_ANCH; i += 1024)
        atomicAdd(&hb[SW3(kb[i] >> 18)], 1u);
    __syncthreads();

    // 2) chunk sums (16 bins/thread) + inclusive suffix scan
    int base = t * 16;
    unsigned s = 0;
    for (int u = 0; u < 16; ++u) s += hb[SW3(base + u)];
    csum[t] = s;
    __syncthreads();
    for (int off = 1; off < 1024; off <<= 1) {
        unsigned v = (t + off < 1024) ? csum[t + off] : 0u;
        __syncthreads();
        csum[t] += v;
        __syncthreads();
    }
    unsigned before = csum[t] - s;   // keys in strictly higher chunks

    // 3) threshold T
    unsigned acc = before;
    for (int bin = base + 15; bin >= base; --bin) {
        unsigned hh = hb[SW3(bin)];
        if (acc + hh >= PRE_NMS) { atomicMax(&sT, (unsigned)bin); break; }
        acc += hh;
    }
    __syncthreads();
    unsigned T = sT;

    // 4) overwrite hist with binbase; capture cnt at T
    acc = before;
    for (int bin = base + 15; bin >= base; --bin) {
        unsigned hh = hb[SW3(bin)];
        if ((unsigned)bin == T) sCnt = acc + hh;
        hb[SW3(bin)] = acc;
        acc += hh;
    }
    __syncthreads();

    // 5) scatter (slot alloc by atomicAdd on binbase)
    for (int i = t; i < N_ANCH; i += 1024) {
        unsigned key = kb[i];
        unsigned bin = key >> 18;
        if (bin >= T) {
            unsigned pos = atomicAdd(&hb[SW3(bin)], 1u);
            if (pos < SEGL) {
                int a = i >> 14, pix = i & (NPIX - 1);
                unsigned idx = (unsigned)(pix * A_NUM + a);
                segl[pos] = ((unsigned long long)key << 32)
                          | (unsigned long long)(0xFFFFFFFFu - idx);
            }
        }
    }
    __syncthreads();
    unsigned n = sCnt; if (n > SEGL) n = SEGL;

    // 6) exact rank + decode into sorted slot
    for (int p = t; p < (int)n; p += 1024) {
        unsigned long long key = segl[p];
        unsigned bin = (unsigned)(key >> 50);
        unsigned end = hb[SW3(bin)];                         // post-alloc = seg end
        unsigned bs  = (bin + 1 < NB3) ? hb[SW3(bin + 1)] : 0u;  // seg base
        if (end > SEGL) end = SEGL;
        unsigned rank = bs;
        for (unsigned q = bs; q < end; ++q)
            rank += (segl[q] > key) ? 1u : 0u;
        if (rank < PRE_NMS) {
            int idx = (int)(0xFFFFFFFFu - (unsigned)(key & 0xFFFFFFFFull));
            float x1, y1, x2, y2; bool v;
            decode_box(b, idx, deltas, im_info, anchors, x1, y1, x2, y2, v);
            *(float4*)(boxes + ((size_t)b * PRE_NMS + rank) * 4) =
                make_float4(x1, y1, x2, y2);
        }
    }
}

// One row of a 64x64 suppression block: inter/uni in the reference's exact
// op order; division eliminated except in the proven +-6e-7*uni band
// (round-6 proof; validated absmax=0). Returns the 64-bit suppress mask.
__device__ __forceinline__ unsigned long long iou_row(
    float4 bi, float ia, float jx1, float jy1, float jx2, float jy2, float ja)
{
    float xx1 = fmaxf(bi.x, jx1);
    float yy1 = fmaxf(bi.y, jy1);
    float xx2 = fminf(bi.z, jx2);
    float yy2 = fminf(bi.w, jy2);
    float iw = fmaxf(0.0f, __fadd_rn(__fsub_rn(xx2, xx1), 1.0f));
    float ih = fmaxf(0.0f, __fadd_rn(__fsub_rn(yy2, yy1), 1.0f));
    float inter = __fmul_rn(iw, ih);
    float uni = __fsub_rn(__fadd_rn(ia, ja), inter);
    float diff = __fsub_rn(inter, __fmul_rn(NMS_THRESH_F, uni));
    unsigned long long sup = __ballot(diff > 0.0f);
    unsigned long long band = __ballot(fabsf(diff) <= __fmul_rn(6e-7f, uni));
    if (band) {   // rare; wave-uniform branch
        unsigned long long supd = __ballot(__fdiv_rn(inter, uni) > NMS_THRESH_F);
        sup = (sup & ~band) | (supd & band);
    }
    return sup;
}

// K3: upper-triangular IoU suppression bitmask, blocked layout
// mask[b][R][C][64] (u64). 256-thread blocks: 4 waves share one row tile
// (LDS loaded once); each wave owns one column PAIR of an 8-column group.
__global__ __launch_bounds__(256) void k_iou_mask(
    const float* __restrict__ boxes, unsigned long long* __restrict__ mask)
{
    int bid = blockIdx.x;
    int b = bid / GT_TILES;
    int g = bid - b * GT_TILES;
    int R = 0;
    while (g >= ((RT_TILES - R + 7) >> 3)) { g -= (RT_TILES - R + 7) >> 3; ++R; }

    int wave = threadIdx.x >> 6;
    int lane = threadIdx.x & 63;
    const float* Bb = boxes + (size_t)b * PRE_NMS * 4;

    __shared__ float4 rb4[64];
    __shared__ float rba[64];
    if (threadIdx.x < 64) {
        int il = R * 64 + threadIdx.x;
        float4 rv = make_float4(0.f, 0.f, -1.f, -1.f);
        if (il < PRE_NMS) rv = *(const float4*)(Bb + 4 * (size_t)il);
        rb4[threadIdx.x] = rv;
        rba[threadIdx.x] = __fmul_rn(__fadd_rn(__fsub_rn(rv.z, rv.x), 1.0f),
                                     __fadd_rn(__fsub_rn(rv.w, rv.y), 1.0f));
    }
    __syncthreads();

    int C1 = R + g * 8 + wave * 2;
    int C2 = C1 + 1;
    if (C1 >= RT_TILES) return;   // tail waves idle (no barriers below)

    float j1x1 = 0.f, j1y1 = 0.f, j1x2 = -1.f, j1y2 = -1.f;
    float j2x1 = 0.f, j2y1 = 0.f, j2x2 = -1.f, j2y2 = -1.f;
    int j1 = C1 * 64 + lane;
    int j2 = C2 * 64 + lane;
    if (j1 < PRE_NMS) {
        float4 v = *(const float4*)(Bb + 4 * (size_t)j1);
        j1x1 = v.x; j1y1 = v.y; j1x2 = v.z; j1y2 = v.w;
    }
    if (C2 < RT_TILES && j2 < PRE_NMS) {
        float4 v = *(const float4*)(Bb + 4 * (size_t)j2);
        j2x1 = v.x; j2y1 = v.y; j2x2 = v.z; j2y2 = v.w;
    }
    float j1a = __fmul_rn(__fadd_rn(__fsub_rn(j1x2, j1x1), 1.0f),
                          __fadd_rn(__fsub_rn(j1y2, j1y1), 1.0f));
    float j2a = __fmul_rn(__fadd_rn(__fsub_rn(j2x2, j2x1), 1.0f),
                          __fadd_rn(__fsub_rn(j2y2, j2y1), 1.0f));

    unsigned long long w1 = 0ULL, w2 = 0ULL;
    if (C1 == R) {   // diagonal tile (g==0, wave==0 only)
        #pragma unroll 4
        for (int ri = 0; ri < 64; ++ri) {
            float4 bi = rb4[ri];
            float ia = rba[ri];
            unsigned long long s1 = iou_row(bi, ia, j1x1, j1y1, j1x2, j1y2, j1a)
                                    & (0xFFFFFFFFFFFFFFFEull << ri);
            unsigned long long s2 = iou_row(bi, ia, j2x1, j2y1, j2x2, j2y2, j2a);
            w1 = (lane == ri) ? s1 : w1;
            w2 = (lane == ri) ? s2 : w2;
        }
    } else {
        #pragma unroll 4
        for (int ri = 0; ri < 64; ++ri) {
            float4 bi = rb4[ri];
            float ia = rba[ri];
            unsigned long long s1 = iou_row(bi, ia, j1x1, j1y1, j1x2, j1y2, j1a);
            unsigned long long s2 = iou_row(bi, ia, j2x1, j2y1, j2x2, j2y2, j2a);
            w1 = (lane == ri) ? s1 : w1;
            w2 = (lane == ri) ? s2 : w2;
        }
    }

    unsigned long long* Mb = mask + (size_t)b * BQWORDS;
    Mb[(size_t)(R * RT_TILES + C1) * 64 + lane] = w1;
    if (C2 < RT_TILES)
        Mb[(size_t)(R * RT_TILES + C2) * 64 + lane] = w2;
}

// K4: serial greedy scan + fused output write. One wave per batch.
// 16-deep unconditional prefetch (static register slots); C<R(i) words
// skipped (exec-masked; zeros replace harmless garbage).
__global__ __launch_bounds__(64) void k_nms_scan(
    const unsigned long long* __restrict__ mask,
    const float* __restrict__ boxes, float* __restrict__ out)
{
    const int b = blockIdx.x;
    const int l = threadIdx.x;
    __shared__ unsigned long long supp[RT_TILES];
    __shared__ int klist[POST_NMS];
    supp[l] = 0ULL;
    if (l < RT_TILES - 64) supp[l + 64] = 0ULL;
    __syncthreads();

    const unsigned long long* __restrict__ M = mask + (size_t)b * BQWORDS;
    int kept = 0;
    unsigned long long curw = 0; int curwi = -1;

#define LOADROW(p0, p1, i) { \
        int _i = ((i) < PRE_NMS) ? (i) : (PRE_NMS - 1); \
        int _R = _i >> 6; \
        const unsigned long long* _r = M + (size_t)(_R * RT_TILES) * 64 + (_i & 63); \
        p0 = 0ULL; p1 = 0ULL; \
        if (l >= _R) p0 = _r[l * 64]; \
        if (l < RT_TILES - 64 && 64 + l >= _R) p1 = _r[(64 + l) * 64]; }

#define STEP(i, p0, p1) { \
        if (kept < POST_NMS) { \
            int _wi = (i) >> 6; \
            if (_wi != curwi) { curw = supp[_wi]; curwi = _wi; } \
            if (!((curw >> ((i) & 63)) & 1ULL)) { \
                if (l == 0) klist[kept] = (i); \
                supp[l] |= p0; \
                if (l < RT_TILES - 64) supp[l + 64] |= p1; \
                ++kept; curwi = -1; \
            } \
        } }

    unsigned long long p[16][2];
    #pragma unroll
    for (int k = 0; k < 16; ++k) { LOADROW(p[k][0], p[k][1], k) }

    for (int i = 0; i < PRE_NMS && kept < POST_NMS; i += 16) {
        #pragma unroll
        for (int k = 0; k < 16; ++k) {
            STEP(i + k, p[k][0], p[k][1])
            LOADROW(p[k][0], p[k][1], i + 16 + k)
        }
    }
    __syncthreads();

    for (int k = l; k < POST_NMS; k += 64) {
        size_t o = ((size_t)b * POST_NMS + k) * 5;
        float x1 = 0.f, y1 = 0.f, x2 = 0.f, y2 = 0.f;
        if (k < kept) {
            int idx = klist[k];
            const float4 v = *(const float4*)(boxes + ((size_t)b * PRE_NMS + idx) * 4);
            x1 = v.x; y1 = v.y; x2 = v.z; y2 = v.w;
        }
        out[o + 0] = (float)b;
        out[o + 1] = x1; out[o + 2] = y1; out[o + 3] = x2; out[o + 4] = y2;
    }
#undef LOADROW
#undef STEP
}

// Fallback NMS (used only if ws_size is too small for the bitmask).
__global__ __launch_bounds__(1024) void k_nms_out(
    const float* __restrict__ boxes, float* __restrict__ out)
{
    __shared__ float bx1[PRE_NMS], by1[PRE_NMS], bx2[PRE_NMS], by2[PRE_NMS], bar[PRE_NMS];
    __shared__ unsigned rem[(PRE_NMS + 31) / 32];
    __shared__ int kept_idx[POST_NMS];

    int b = blockIdx.x;
    int t = threadIdx.x;

    for (int p = t; p < PRE_NMS; p += 1024) {
        size_t o = ((size_t)b * PRE_NMS + p) * 4;
        float x1 = boxes[o], y1 = boxes[o + 1], x2 = boxes[o + 2], y2 = boxes[o + 3];
        bx1[p] = x1; by1[p] = y1; bx2[p] = x2; by2[p] = y2;
        bar[p] = __fmul_rn(__fadd_rn(__fsub_rn(x2, x1), 1.0f),
                           __fadd_rn(__fsub_rn(y2, y1), 1.0f));
    }
    for (int p = t; p < (PRE_NMS + 31) / 32; p += 1024) rem[p] = 0u;
    __syncthreads();

    int kept = 0;
    for (int i = 0; i < PRE_NMS && kept < POST_NMS; ++i) {
        if (rem[i >> 5] & (1u << (i & 31))) continue;
        if (t == 0) kept_idx[kept] = i;
        float xi1 = bx1[i], yi1 = by1[i], xi2 = bx2[i], yi2 = by2[i], ai = bar[i];
        for (int j = i + 1 + t; j < PRE_NMS; j += 1024) {
            float xx1 = fmaxf(xi1, bx1[j]);
            float yy1 = fmaxf(yi1, by1[j]);
            float xx2 = fminf(xi2, bx2[j]);
            float yy2 = fminf(yi2, by2[j]);
            float iw = fmaxf(0.0f, __fadd_rn(__fsub_rn(xx2, xx1), 1.0f));
            float ih = fmaxf(0.0f, __fadd_rn(__fsub_rn(yy2, yy1), 1.0f));
            float inter = __fmul_rn(iw, ih);
            if (inter > 0.0f) {
                float uni = __fsub_rn(__fadd_rn(ai, bar[j]), inter);
                float iou = __fdiv_rn(inter, uni);
                if (iou > NMS_THRESH_F) atomicOr(&rem[j >> 5], 1u << (j & 31));
            }
        }
        ++kept;
        __syncthreads();
    }

    for (int k = t; k < POST_NMS; k += 1024) {
        size_t o = ((size_t)b * POST_NMS + k) * 5;
        out[o] = (float)b;
        if (k < kept) {
            int ii = kept_idx[k];
            out[o + 1] = bx1[ii]; out[o + 2] = by1[ii];
            out[o + 3] = bx2[ii]; out[o + 4] = by2[ii];
        } else {
            out[o + 1] = 0.0f; out[o + 2] = 0.0f; out[o + 3] = 0.0f; out[o + 4] = 0.0f;
        }
    }
}

extern "C" void kernel_launch(void* const* d_in, const int* in_sizes, int n_in,
                              void* d_out, int out_size, void* d_ws, size_t ws_size,
                              hipStream_t stream)
{
    const float* scores  = (const float*)d_in[0];
    const float* deltas  = (const float*)d_in[1];
    const float* im_info = (const float*)d_in[2];
    const float* anchors = (const float*)d_in[3];
    float* out = (float*)d_out;
    char* ws = (char*)d_ws;

    unsigned* keys             = (unsigned*)(ws + OFF_KEYS);
    float* boxes               = (float*)(ws + OFF_BOXES);
    unsigned long long* mask   = (unsigned long long*)(ws + OFF_MASK);

    int total = B_NUM * N_ANCH;
    int blk = 256;
    k_decode<<<(total + blk - 1) / blk, blk, 0, stream>>>(
        scores, deltas, im_info, anchors, keys);
    k_select<<<B_NUM, 1024, 0, stream>>>(keys, deltas, im_info, anchors, boxes);

    if (ws_size >= (size_t)OFF_MASK + MASK_BYTES) {
        k_iou_mask<<<B_NUM * GT_TILES, 256, 0, stream>>>(boxes, mask);
        k_nms_scan<<<B_NUM, 64, 0, stream>>>(mask, boxes, out);
    } else {
        k_nms_out<<<B_NUM, 1024, 0, stream>>>(boxes, out);
    }
}

// Round 13
// 296.858 us; speedup vs baseline: 1.1428x; 1.1428x over previous
//
#include <hip/hip_runtime.h>
#include <stdint.h>

#define FEAT_STRIDE_I 16
#define A_NUM 9
#define HH 128
#define WW 128
#define NPIX (HH * WW)            // 16384
#define N_ANCH (NPIX * A_NUM)     // 147456
#define B_NUM 8
#define PRE_NMS 6000
#define POST_NMS 300
#define NMS_THRESH_F 0.7f
#define MIN_SIZE_F 16.0f
#define NEG_INF_F -1e30f

#define NB3 16384                  // 14-bit bins (key>>18)
#define SW3(i) ((i) + ((i) >> 5))  // LDS swizzle
#define SEGL 8192                  // in-LDS candidate segment cap

#define RT_TILES 94                // ceil(6000/64)
#define GT_TILES 600               // sum_R ceil((94-R)/8): 8-column groups
#define BQWORDS (RT_TILES * RT_TILES * 64)   // 565,504 qwords per batch

// ---- workspace layout (bytes) ----
#define OFF_KEYS  0u               // 8*147456*4 = 4,718,592
#define OFF_BOXES 4718592u         // 8*6000*4*4 = 768,000
#define OFF_MASK  5486592u         // 8*565504*8 = 36,192,256 -> end 41.7 MB
#define MASK_BYTES ((size_t)B_NUM * BQWORDS * 8)

__device__ __forceinline__ unsigned sortable_f32(float f) {
    unsigned u = __float_as_uint(f);
    return (u & 0x80000000u) ? ~u : (u | 0x80000000u);
}

// Decode one anchor's box exactly in the reference's op order.
__device__ __forceinline__ void decode_box(
    int b, int idx,
    const float* __restrict__ deltas, const float* __restrict__ im_info,
    const float* __restrict__ anchors,
    float& x1, float& y1, float& x2, float& y2, bool& valid)
{
    int a   = idx % A_NUM;
    int pix = idx / A_NUM;
    int w   = pix & (WW - 1);
    int h   = pix >> 7;

    float a0 = anchors[a * 4 + 0];
    float a1 = anchors[a * 4 + 1];
    float a2 = anchors[a * 4 + 2];
    float a3 = anchors[a * 4 + 3];

    float aw = __fadd_rn(__fsub_rn(a2, a0), 1.0f);
    float ah = __fadd_rn(__fsub_rn(a3, a1), 1.0f);
    float sx = (float)(w * FEAT_STRIDE_I);
    float sy = (float)(h * FEAT_STRIDE_I);
    float acx = __fadd_rn(__fadd_rn(sx, a0), __fmul_rn(0.5f, aw));
    float acy = __fadd_rn(__fadd_rn(sy, a1), __fmul_rn(0.5f, ah));

    size_t base = ((size_t)b * 36 + 4 * a) * NPIX + pix;
    float dx = deltas[base];
    float dy = deltas[base + NPIX];
    float dw = deltas[base + 2 * (size_t)NPIX];
    float dh = deltas[base + 3 * (size_t)NPIX];

    float pcx = __fadd_rn(__fmul_rn(dx, aw), acx);
    float pcy = __fadd_rn(__fmul_rn(dy, ah), acy);
    float pw  = __fmul_rn(expf(dw), aw);
    float ph  = __fmul_rn(expf(dh), ah);

    float hx = __fmul_rn(0.5f, pw);
    float hy = __fmul_rn(0.5f, ph);
    x1 = __fsub_rn(pcx, hx);
    y1 = __fsub_rn(pcy, hy);
    x2 = __fadd_rn(pcx, hx);
    y2 = __fadd_rn(pcy, hy);

    float im_h = im_info[b * 3 + 0];
    float im_w = im_info[b * 3 + 1];
    float sc   = im_info[b * 3 + 2];
    float wmax = __fsub_rn(im_w, 1.0f);
    float hmax = __fsub_rn(im_h, 1.0f);

    x1 = fminf(fmaxf(x1, 0.0f), wmax);
    y1 = fminf(fmaxf(y1, 0.0f), hmax);
    x2 = fminf(fmaxf(x2, 0.0f), wmax);
    y2 = fminf(fmaxf(y2, 0.0f), hmax);

    float min_sz = __fmul_rn(MIN_SIZE_F, sc);
    valid = (__fadd_rn(__fsub_rn(x2, x1), 1.0f) >= min_sz) &&
            (__fadd_rn(__fsub_rn(y2, y1), 1.0f) >= min_sz);
}

// K1: decode + masked score -> sortable key. Pure streaming, no atomics.
__global__ void k_decode(
    const float* __restrict__ scores, const float* __restrict__ deltas,
    const float* __restrict__ im_info, const float* __restrict__ anchors,
    unsigned* __restrict__ keys)
{
    int gt = blockIdx.x * blockDim.x + threadIdx.x;
    if (gt >= B_NUM * N_ANCH) return;
    int pix  = gt & (NPIX - 1);
    int rest = gt >> 14;
    int a = rest % A_NUM;
    int b = rest / A_NUM;
    int idx = pix * A_NUM + a;

    float x1, y1, x2, y2; bool valid;
    decode_box(b, idx, deltas, im_info, anchors, x1, y1, x2, y2, valid);

    float s = scores[((size_t)b * 18 + 9 + a) * NPIX + pix];
    if (!valid) s = NEG_INF_F;
    keys[gt] = sortable_f32(s);
}

// K2 (fused): per-batch top-6000 selection entirely in LDS.
// Round-13 fix: both global-key passes (hist, scatter) were single-
// outstanding-load latency chains (54 GB/s measured -> ~190us). Now each
// thread stages 4 independent uint4 loads (16 keys, 4KB/wave in flight)
// before touching LDS: 9 round-trips instead of 144 per pass.
__global__ __launch_bounds__(1024) void k_select(
    const unsigned* __restrict__ keys,
    const float* __restrict__ deltas, const float* __restrict__ im_info,
    const float* __restrict__ anchors, float* __restrict__ boxes)
{
    __shared__ unsigned hb[SW3(NB3 - 1) + 2];      // 67.6 KB
    __shared__ unsigned long long segl[SEGL];      // 64 KB
    __shared__ unsigned csum[1024];
    __shared__ unsigned sT, sCnt;

    int b = blockIdx.x;
    int t = threadIdx.x;
    if (t == 0) { sT = 0; sCnt = 0; }
    for (int i = t; i < SW3(NB3 - 1) + 2; i += 1024) hb[i] = 0u;
    __syncthreads();

    const unsigned* kb = keys + (size_t)b * N_ANCH;
    const uint4* kb4 = (const uint4*)kb;           // N_ANCH/4 = 36864 uint4

    // 1) histogram — 9 iterations, 16 keys/thread/iter, loads staged first
    for (int it = 0; it < N_ANCH / 4; it += 4096) {
        uint4 v0 = kb4[it + t];
        uint4 v1 = kb4[it + t + 1024];
        uint4 v2 = kb4[it + t + 2048];
        uint4 v3 = kb4[it + t + 3072];
        atomicAdd(&hb[SW3(v0.x >> 18)], 1u);
        atomicAdd(&hb[SW3(v0.y >> 18)], 1u);
        atomicAdd(&hb[SW3(v0.z >> 18)], 1u);
        atomicAdd(&hb[SW3(v0.w >> 18)], 1u);
        atomicAdd(&hb[SW3(v1.x >> 18)], 1u);
        atomicAdd(&hb[SW3(v1.y >> 18)], 1u);
        atomicAdd(&hb[SW3(v1.z >> 18)], 1u);
        atomicAdd(&hb[SW3(v1.w >> 18)], 1u);
        atomicAdd(&hb[SW3(v2.x >> 18)], 1u);
        atomicAdd(&hb[SW3(v2.y >> 18)], 1u);
        atomicAdd(&hb[SW3(v2.z >> 18)], 1u);
        atomicAdd(&hb[SW3(v2.w >> 18)], 1u);
        atomicAdd(&hb[SW3(v3.x >> 18)], 1u);
        atomicAdd(&hb[SW3(v3.y >> 18)], 1u);
        atomicAdd(&hb[SW3(v3.z >> 18)], 1u);
        atomicAdd(&hb[SW3(v3.w >> 18)], 1u);
    }
    __syncthreads();

    // 2) chunk sums (16 bins/thread) + inclusive suffix scan
    int base = t * 16;
    unsigned s = 0;
    for (int u = 0; u < 16; ++u) s += hb[SW3(base + u)];
    csum[t] = s;
    __syncthreads();
    for (int off = 1; off < 1024; off <<= 1) {
        unsigned v = (t + off < 1024) ? csum[t + off] : 0u;
        __syncthreads();
        csum[t] += v;
        __syncthreads();
    }
    unsigned before = csum[t] - s;   // keys in strictly higher chunks

    // 3) threshold T
    unsigned acc = before;
    for (int bin = base + 15; bin >= base; --bin) {
        unsigned hh = hb[SW3(bin)];
        if (acc + hh >= PRE_NMS) { atomicMax(&sT, (unsigned)bin); break; }
        acc += hh;
    }
    __syncthreads();
    unsigned T = sT;

    // 4) overwrite hist with binbase; capture cnt at T
    acc = before;
    for (int bin = base + 15; bin >= base; --bin) {
        unsigned hh = hb[SW3(bin)];
        if ((unsigned)bin == T) sCnt = acc + hh;
        hb[SW3(bin)] = acc;
        acc += hh;
    }
    __syncthreads();

    // 5) scatter (slot alloc by atomicAdd on binbase), loads staged first
#define SCAT(key, i) { \
        unsigned _bin = (key) >> 18; \
        if (_bin >= T) { \
            unsigned _pos = atomicAdd(&hb[SW3(_bin)], 1u); \
            if (_pos < SEGL) { \
                int _a = (i) >> 14, _pix = (i) & (NPIX - 1); \
                unsigned _idx = (unsigned)(_pix * A_NUM + _a); \
                segl[_pos] = ((unsigned long long)(key) << 32) \
                           | (unsigned long long)(0xFFFFFFFFu - _idx); \
            } \
        } }

    for (int it = 0; it < N_ANCH / 4; it += 4096) {
        int q0 = it + t, q1 = q0 + 1024, q2 = q0 + 2048, q3 = q0 + 3072;
        uint4 v0 = kb4[q0];
        uint4 v1 = kb4[q1];
        uint4 v2 = kb4[q2];
        uint4 v3 = kb4[q3];
        SCAT(v0.x, 4 * q0 + 0) SCAT(v0.y, 4 * q0 + 1)
        SCAT(v0.z, 4 * q0 + 2) SCAT(v0.w, 4 * q0 + 3)
        SCAT(v1.x, 4 * q1 + 0) SCAT(v1.y, 4 * q1 + 1)
        SCAT(v1.z, 4 * q1 + 2) SCAT(v1.w, 4 * q1 + 3)
        SCAT(v2.x, 4 * q2 + 0) SCAT(v2.y, 4 * q2 + 1)
        SCAT(v2.z, 4 * q2 + 2) SCAT(v2.w, 4 * q2 + 3)
        SCAT(v3.x, 4 * q3 + 0) SCAT(v3.y, 4 * q3 + 1)
        SCAT(v3.z, 4 * q3 + 2) SCAT(v3.w, 4 * q3 + 3)
    }
#undef SCAT
    __syncthreads();
    unsigned n = sCnt; if (n > SEGL) n = SEGL;

    // 6) exact rank + decode into sorted slot
    for (int p = t; p < (int)n; p += 1024) {
        unsigned long long key = segl[p];
        unsigned bin = (unsigned)(key >> 50);
        unsigned end = hb[SW3(bin)];                         // post-alloc = seg end
        unsigned bs  = (bin + 1 < NB3) ? hb[SW3(bin + 1)] : 0u;  // seg base
        if (end > SEGL) end = SEGL;
        unsigned rank = bs;
        for (unsigned q = bs; q < end; ++q)
            rank += (segl[q] > key) ? 1u : 0u;
        if (rank < PRE_NMS) {
            int idx = (int)(0xFFFFFFFFu - (unsigned)(key & 0xFFFFFFFFull));
            float x1, y1, x2, y2; bool v;
            decode_box(b, idx, deltas, im_info, anchors, x1, y1, x2, y2, v);
            *(float4*)(boxes + ((size_t)b * PRE_NMS + rank) * 4) =
                make_float4(x1, y1, x2, y2);
        }
    }
}

// One row of a 64x64 suppression block: inter/uni in the reference's exact
// op order; division eliminated except in the proven +-6e-7*uni band
// (round-6 proof; validated absmax=0). Returns the 64-bit suppress mask.
__device__ __forceinline__ unsigned long long iou_row(
    float4 bi, float ia, float jx1, float jy1, float jx2, float jy2, float ja)
{
    float xx1 = fmaxf(bi.x, jx1);
    float yy1 = fmaxf(bi.y, jy1);
    float xx2 = fminf(bi.z, jx2);
    float yy2 = fminf(bi.w, jy2);
    float iw = fmaxf(0.0f, __fadd_rn(__fsub_rn(xx2, xx1), 1.0f));
    float ih = fmaxf(0.0f, __fadd_rn(__fsub_rn(yy2, yy1), 1.0f));
    float inter = __fmul_rn(iw, ih);
    float uni = __fsub_rn(__fadd_rn(ia, ja), inter);
    float diff = __fsub_rn(inter, __fmul_rn(NMS_THRESH_F, uni));
    unsigned long long sup = __ballot(diff > 0.0f);
    unsigned long long band = __ballot(fabsf(diff) <= __fmul_rn(6e-7f, uni));
    if (band) {   // rare; wave-uniform branch
        unsigned long long supd = __ballot(__fdiv_rn(inter, uni) > NMS_THRESH_F);
        sup = (sup & ~band) | (supd & band);
    }
    return sup;
}

// K3: upper-triangular IoU suppression bitmask, blocked layout
// mask[b][R][C][64] (u64). 256-thread blocks: 4 waves share one row tile
// (LDS loaded once); each wave owns one column PAIR of an 8-column group.
__global__ __launch_bounds__(256) void k_iou_mask(
    const float* __restrict__ boxes, unsigned long long* __restrict__ mask)
{
    int bid = blockIdx.x;
    int b = bid / GT_TILES;
    int g = bid - b * GT_TILES;
    int R = 0;
    while (g >= ((RT_TILES - R + 7) >> 3)) { g -= (RT_TILES - R + 7) >> 3; ++R; }

    int wave = threadIdx.x >> 6;
    int lane = threadIdx.x & 63;
    const float* Bb = boxes + (size_t)b * PRE_NMS * 4;

    __shared__ float4 rb4[64];
    __shared__ float rba[64];
    if (threadIdx.x < 64) {
        int il = R * 64 + threadIdx.x;
        float4 rv = make_float4(0.f, 0.f, -1.f, -1.f);
        if (il < PRE_NMS) rv = *(const float4*)(Bb + 4 * (size_t)il);
        rb4[threadIdx.x] = rv;
        rba[threadIdx.x] = __fmul_rn(__fadd_rn(__fsub_rn(rv.z, rv.x), 1.0f),
                                     __fadd_rn(__fsub_rn(rv.w, rv.y), 1.0f));
    }
    __syncthreads();

    int C1 = R + g * 8 + wave * 2;
    int C2 = C1 + 1;
    if (C1 >= RT_TILES) return;   // tail waves idle (no barriers below)

    float j1x1 = 0.f, j1y1 = 0.f, j1x2 = -1.f, j1y2 = -1.f;
    float j2x1 = 0.f, j2y1 = 0.f, j2x2 = -1.f, j2y2 = -1.f;
    int j1 = C1 * 64 + lane;
    int j2 = C2 * 64 + lane;
    if (j1 < PRE_NMS) {
        float4 v = *(const float4*)(Bb + 4 * (size_t)j1);
        j1x1 = v.x; j1y1 = v.y; j1x2 = v.z; j1y2 = v.w;
    }
    if (C2 < RT_TILES && j2 < PRE_NMS) {
        float4 v = *(const float4*)(Bb + 4 * (size_t)j2);
        j2x1 = v.x; j2y1 = v.y; j2x2 = v.z; j2y2 = v.w;
    }
    float j1a = __fmul_rn(__fadd_rn(__fsub_rn(j1x2, j1x1), 1.0f),
                          __fadd_rn(__fsub_rn(j1y2, j1y1), 1.0f));
    float j2a = __fmul_rn(__fadd_rn(__fsub_rn(j2x2, j2x1), 1.0f),
                          __fadd_rn(__fsub_rn(j2y2, j2y1), 1.0f));

    unsigned long long w1 = 0ULL, w2 = 0ULL;
    if (C1 == R) {   // diagonal tile (g==0, wave==0 only)
        #pragma unroll 4
        for (int ri = 0; ri < 64; ++ri) {
            float4 bi = rb4[ri];
            float ia = rba[ri];
            unsigned long long s1 = iou_row(bi, ia, j1x1, j1y1, j1x2, j1y2, j1a)
                                    & (0xFFFFFFFFFFFFFFFEull << ri);
            unsigned long long s2 = iou_row(bi, ia, j2x1, j2y1, j2x2, j2y2, j2a);
            w1 = (lane == ri) ? s1 : w1;
            w2 = (lane == ri) ? s2 : w2;
        }
    } else {
        #pragma unroll 4
        for (int ri = 0; ri < 64; ++ri) {
            float4 bi = rb4[ri];
            float ia = rba[ri];
            unsigned long long s1 = iou_row(bi, ia, j1x1, j1y1, j1x2, j1y2, j1a);
            unsigned long long s2 = iou_row(bi, ia, j2x1, j2y1, j2x2, j2y2, j2a);
            w1 = (lane == ri) ? s1 : w1;
            w2 = (lane == ri) ? s2 : w2;
        }
    }

    unsigned long long* Mb = mask + (size_t)b * BQWORDS;
    Mb[(size_t)(R * RT_TILES + C1) * 64 + lane] = w1;
    if (C2 < RT_TILES)
        Mb[(size_t)(R * RT_TILES + C2) * 64 + lane] = w2;
}

// K4: serial greedy scan + fused output write. One wave per batch.
// 16-deep unconditional prefetch (static register slots); C<R(i) words
// skipped (exec-masked; zeros replace harmless garbage).
__global__ __launch_bounds__(64) void k_nms_scan(
    const unsigned long long* __restrict__ mask,
    const float* __restrict__ boxes, float* __restrict__ out)
{
    const int b = blockIdx.x;
    const int l = threadIdx.x;
    __shared__ unsigned long long supp[RT_TILES];
    __shared__ int klist[POST_NMS];
    supp[l] = 0ULL;
    if (l < RT_TILES - 64) supp[l + 64] = 0ULL;
    __syncthreads();

    const unsigned long long* __restrict__ M = mask + (size_t)b * BQWORDS;
    int kept = 0;
    unsigned long long curw = 0; int curwi = -1;

#define LOADROW(p0, p1, i) { \
        int _i = ((i) < PRE_NMS) ? (i) : (PRE_NMS - 1); \
        int _R = _i >> 6; \
        const unsigned long long* _r = M + (size_t)(_R * RT_TILES) * 64 + (_i & 63); \
        p0 = 0ULL; p1 = 0ULL; \
        if (l >= _R) p0 = _r[l * 64]; \
        if (l < RT_TILES - 64 && 64 + l >= _R) p1 = _r[(64 + l) * 64]; }

#define STEP(i, p0, p1) { \
        if (kept < POST_NMS) { \
            int _wi = (i) >> 6; \
            if (_wi != curwi) { curw = supp[_wi]; curwi = _wi; } \
            if (!((curw >> ((i) & 63)) & 1ULL)) { \
                if (l == 0) klist[kept] = (i); \
                supp[l] |= p0; \
                if (l < RT_TILES - 64) supp[l + 64] |= p1; \
                ++kept; curwi = -1; \
            } \
        } }

    unsigned long long p[16][2];
    #pragma unroll
    for (int k = 0; k < 16; ++k) { LOADROW(p[k][0], p[k][1], k) }

    for (int i = 0; i < PRE_NMS && kept < POST_NMS; i += 16) {
        #pragma unroll
        for (int k = 0; k < 16; ++k) {
            STEP(i + k, p[k][0], p[k][1])
            LOADROW(p[k][0], p[k][1], i + 16 + k)
        }
    }
    __syncthreads();

    for (int k = l; k < POST_NMS; k += 64) {
        size_t o = ((size_t)b * POST_NMS + k) * 5;
        float x1 = 0.f, y1 = 0.f, x2 = 0.f, y2 = 0.f;
        if (k < kept) {
            int idx = klist[k];
            const float4 v = *(const float4*)(boxes + ((size_t)b * PRE_NMS + idx) * 4);
            x1 = v.x; y1 = v.y; x2 = v.z; y2 = v.w;
        }
        out[o + 0] = (float)b;
        out[o + 1] = x1; out[o + 2] = y1; out[o + 3] = x2; out[o + 4] = y2;
    }
#undef LOADROW
#undef STEP
}

// Fallback NMS (used only if ws_size is too small for the bitmask).
__global__ __launch_bounds__(1024) void k_nms_out(
    const float* __restrict__ boxes, float* __restrict__ out)
{
    __shared__ float bx1[PRE_NMS], by1[PRE_NMS], bx2[PRE_NMS], by2[PRE_NMS], bar[PRE_NMS];
    __shared__ unsigned rem[(PRE_NMS + 31) / 32];
    __shared__ int kept_idx[POST_NMS];

    int b = blockIdx.x;
    int t = threadIdx.x;

    for (int p = t; p < PRE_NMS; p += 1024) {
        size_t o = ((size_t)b * PRE_NMS + p) * 4;
        float x1 = boxes[o], y1 = boxes[o + 1], x2 = boxes[o + 2], y2 = boxes[o + 3];
        bx1[p] = x1; by1[p] = y1; bx2[p] = x2; by2[p] = y2;
        bar[p] = __fmul_rn(__fadd_rn(__fsub_rn(x2, x1), 1.0f),
                           __fadd_rn(__fsub_rn(y2, y1), 1.0f));
    }
    for (int p = t; p < (PRE_NMS + 31) / 32; p += 1024) rem[p] = 0u;
    __syncthreads();

    int kept = 0;
    for (int i = 0; i < PRE_NMS && kept < POST_NMS; ++i) {
        if (rem[i >> 5] & (1u << (i & 31))) continue;
        if (t == 0) kept_idx[kept] = i;
        float xi1 = bx1[i], yi1 = by1[i], xi2 = bx2[i], yi2 = by2[i], ai = bar[i];
        for (int j = i + 1 + t; j < PRE_NMS; j += 1024) {
            float xx1 = fmaxf(xi1, bx1[j]);
            float yy1 = fmaxf(yi1, by1[j]);
            float xx2 = fminf(xi2, bx2[j]);
            float yy2 = fminf(yi2, by2[j]);
            float iw = fmaxf(0.0f, __fadd_rn(__fsub_rn(xx2, xx1), 1.0f));
            float ih = fmaxf(0.0f, __fadd_rn(__fsub_rn(yy2, yy1), 1.0f));
            float inter = __fmul_rn(iw, ih);
            if (inter > 0.0f) {
                float uni = __fsub_rn(__fadd_rn(ai, bar[j]), inter);
                float iou = __fdiv_rn(inter, uni);
                if (iou > NMS_THRESH_F) atomicOr(&rem[j >> 5], 1u << (j & 31));
            }
        }
        ++kept;
        __syncthreads();
    }

    for (int k = t; k < POST_NMS; k += 1024) {
        size_t o = ((size_t)b * POST_NMS + k) * 5;
        out[o] = (float)b;
        if (k < kept) {
            int ii = kept_idx[k];
            out[o + 1] = bx1[ii]; out[o + 2] = by1[ii];
            out[o + 3] = bx2[ii]; out[o + 4] = by2[ii];
        } else {
            out[o + 1] = 0.0f; out[o + 2] = 0.0f; out[o + 3] = 0.0f; out[o + 4] = 0.0f;
        }
    }
}

extern "C" void kernel_launch(void* const* d_in, const int* in_sizes, int n_in,
                              void* d_out, int out_size, void* d_ws, size_t ws_size,
                              hipStream_t stream)
{
    const float* scores  = (const float*)d_in[0];
    const float* deltas  = (const float*)d_in[1];
    const float* im_info = (const float*)d_in[2];
    const float* anchors = (const float*)d_in[3];
    float* out = (float*)d_out;
    char* ws = (char*)d_ws;

    unsigned* keys             = (unsigned*)(ws + OFF_KEYS);
    float* boxes               = (float*)(ws + OFF_BOXES);
    unsigned long long* mask   = (unsigned long long*)(ws + OFF_MASK);

    int total = B_NUM * N_ANCH;
    int blk = 256;
    k_decode<<<(total + blk - 1) / blk, blk, 0, stream>>>(
        scores, deltas, im_info, anchors, keys);
    k_select<<<B_NUM, 1024, 0, stream>>>(keys, deltas, im_info, anchors, boxes);

    if (ws_size >= (size_t)OFF_MASK + MASK_BYTES) {
        k_iou_mask<<<B_NUM * GT_TILES, 256, 0, stream>>>(boxes, mask);
        k_nms_scan<<<B_NUM, 64, 0, stream>>>(mask, boxes, out);
    } else {
        k_nms_out<<<B_NUM, 1024, 0, stream>>>(boxes, out);
    }
}